// Round 4
// baseline (156.998 us; speedup 1.0000x reference)
//
#include <hip/hip_runtime.h>
#include <hip/hip_bf16.h>
#include <cstdint>
#include <cstddef>

// Round 14: I/O vectorization of the non-attn kernels (k_attn kept from R13).
// - k_prep: 64x64 tiles, float4 loads, LDS transpose, short8 (16B) stores.
// - k_qkv: Q/K epilogues via LDS [64n][136o] bf16 transpose -> 16B stores.
// - k_out: epilogue via LDS fp32 half-tiles -> float4 stores (256B runs).
// Compute cores (GEMM K-loops, attention loop) byte-identical to verified R13.

#define NB 4
#define CIN 256
#define CHID 128
#define HEADS 4
#define CHEAD 32
#define NPOS 4096      // 64*64
#define BH 16          // NB*HEADS
#define NTOT 16384     // NB*NPOS
#define QKV_O 384
// 32^-0.5 * log2(e): Q pre-scaled so softmax logits feed exp2 directly
#define QSCALE_LOG2E 0.2550348229f

typedef float f32x2 __attribute__((ext_vector_type(2)));
typedef float f32x4 __attribute__((ext_vector_type(4)));
typedef float f32x16 __attribute__((ext_vector_type(16)));
typedef short s16x8 __attribute__((ext_vector_type(8)));

static __device__ __forceinline__ unsigned short f2bf(float f) {
    union { float f; unsigned u; } v; v.f = f;
    unsigned r = v.u + 0x7FFFu + ((v.u >> 16) & 1u);
    return (unsigned short)(r >> 16);
}

static __device__ __forceinline__ unsigned int pk2bf(float a, float b) {
    union { __hip_bfloat162 h; unsigned int u; } c;
    c.h = __float22bfloat162_rn(float2{a, b});
    return c.u;
}

// Exchange upper-half lanes of a with lower-half lanes of b (gfx950 VALU op).
static __device__ __forceinline__ void plswap(unsigned& a, unsigned& b) {
#if __has_builtin(__builtin_amdgcn_permlane32_swap)
    auto r = __builtin_amdgcn_permlane32_swap((int)a, (int)b, false, false);
    a = (unsigned)r[0];
    b = (unsigned)r[1];
#else
    int hh = (threadIdx.x >> 5) & 1;
    unsigned ta = (unsigned)__shfl_xor((int)a, 32);
    unsigned tb = (unsigned)__shfl_xor((int)b, 32);
    unsigned na = hh ? tb : a;
    unsigned nb = hh ? b : ta;
    a = na; b = nb;
#endif
}

static __device__ __forceinline__ s16x8 mk8(unsigned a, unsigned b, unsigned c, unsigned d) {
    union { unsigned u[4]; s16x8 v; } x;
    x.u[0] = a; x.u[1] = b; x.u[2] = c; x.u[3] = d;
    return x.v;
}

static __device__ __forceinline__ void async_cp16(const void* g, void* l) {
    __builtin_amdgcn_global_load_lds((const __attribute__((address_space(1))) unsigned int*)g,
                                     (__attribute__((address_space(3))) unsigned int*)l, 16, 0, 0);
}

#define MFMA32(a, b, c) __builtin_amdgcn_mfma_f32_32x32x16_bf16(a, b, c, 0, 0, 0)

// K fragment-order layout: K_frag[bh][g=key>>5][f=ch>>4][lane][8 shorts]
//   lane = ((ch>>3)&1)<<5 | (key&31), short j = ch&7  -> 1KB per (g,f) frag.
// V fragment-order layout: V_frag[bh][kc=key>>4][lane][8 shorts]
//   lane = ((key>>3)&1)<<5 | ch, short j = key&7      -> 1KB per kc frag.

// ---------------- kernel 1: transpose x -> xT bf16, fused weight convert ----------------
// 64x64 tiles: float4 coalesced loads, LDS transpose, short8 coalesced stores.
#define PTILES (NB * (CIN / 64) * (NPOS / 64))   // 4*4*64 = 1024
__global__ __launch_bounds__(256) void k_prep(const float* __restrict__ x,
                                              unsigned short* __restrict__ xT,
                                              const float* __restrict__ wqkv,
                                              const float* __restrict__ wout,
                                              unsigned short* __restrict__ wqkv_bf,
                                              unsigned short* __restrict__ wout_bf) {
    if (blockIdx.x >= PTILES) {   // weight-convert tail blocks
        int i = (blockIdx.x - PTILES) * 256 + threadIdx.x;
        if (i < QKV_O * CIN) wqkv_bf[i] = f2bf(wqkv[i]);
        if (i < CIN * CHID)  wout_bf[i] = f2bf(wout[i]);
        return;
    }
    __shared__ float tile[64][65];
    const int per_b = (CIN / 64) * (NPOS / 64);   // 256
    int b   = blockIdx.x / per_b;
    int rem = blockIdx.x % per_b;
    int ct = rem / (NPOS / 64);   // 0..3
    int nt = rem % (NPOS / 64);   // 0..63
    int c0 = ct * 64, n0 = nt * 64;
    int t = threadIdx.x;
    const float* xb = x + (size_t)b * CIN * NPOS;
#pragma unroll
    for (int it = 0; it < 4; ++it) {
        int c  = (t >> 4) + it * 16;
        int n4 = (t & 15) * 4;
        f32x4 v = *(const f32x4*)(xb + (size_t)(c0 + c) * NPOS + n0 + n4);
        tile[c][n4] = v[0]; tile[c][n4 + 1] = v[1];
        tile[c][n4 + 2] = v[2]; tile[c][n4 + 3] = v[3];
    }
    __syncthreads();
    unsigned short* xTb = xT + (size_t)b * NPOS * CIN;
#pragma unroll
    for (int it = 0; it < 2; ++it) {
        int slot = it * 256 + t;
        int n  = slot >> 3;          // 0..63
        int c8 = (slot & 7) * 8;     // 0..56
        union { unsigned short u[8]; s16x8 v; } pk;
#pragma unroll
        for (int r = 0; r < 8; ++r) pk.u[r] = f2bf(tile[c8 + r][n]);
        *(s16x8*)(xTb + (size_t)(n0 + n) * CIN + c0 + c8) = pk.v;
    }
}

// ---------------- kernel 2: QKV projection GEMM, LDS-staged ----------------
// mt==0 -> Q, mt==1 -> K (fragment order), mt==2 -> V (fragment order)
__global__ __launch_bounds__(256, 4) void k_qkv(const unsigned short* __restrict__ wq,
                                                const unsigned short* __restrict__ xT,
                                                unsigned short* __restrict__ Q,
                                                unsigned short* __restrict__ K,
                                                unsigned short* __restrict__ V) {
    __shared__ __align__(16) unsigned char smem[2 * 12288];   // 24 KB
    int mt = blockIdx.x % 3;
    int nt = blockIdx.x / 3;
    int wid = threadIdx.x >> 6, lane = threadIdx.x & 63;
    int quad = lane >> 4, low4 = lane & 15;
    int o0 = mt * 128, n0 = nt * 64;
    int lb = lane * 16;

    const unsigned short* srcA0 = wq + (size_t)(o0 + wid * 32 + low4) * CIN + quad * 8;
    const unsigned short* srcA1 = srcA0 + 16 * CIN;
    const unsigned short* srcB  = xT + (size_t)(n0 + wid * 16 + low4) * CIN + quad * 8;
    int dA0 = wid * 2048, dA1 = dA0 + 1024, dB = 8192 + wid * 1024;

    async_cp16(srcA0, smem + dA0 + lb);
    async_cp16(srcA1, smem + dA1 + lb);
    async_cp16(srcB,  smem + dB  + lb);
    __syncthreads();

    f32x4 acc[2][4] = {};
    for (int c = 0; c < 8; ++c) {
        if (c < 7) {
            unsigned char* nxt = smem + ((c + 1) & 1) * 12288;
            async_cp16(srcA0 + (c + 1) * 32, nxt + dA0 + lb);
            async_cp16(srcA1 + (c + 1) * 32, nxt + dA1 + lb);
            async_cp16(srcB  + (c + 1) * 32, nxt + dB  + lb);
        }
        const unsigned char* cur = smem + (c & 1) * 12288;
        s16x8 a0 = *(const s16x8*)(cur + wid * 2048 + lb);
        s16x8 a1 = *(const s16x8*)(cur + wid * 2048 + 1024 + lb);
#pragma unroll
        for (int j = 0; j < 4; ++j) {
            s16x8 bj = *(const s16x8*)(cur + 8192 + j * 1024 + lb);
            acc[0][j] = __builtin_amdgcn_mfma_f32_16x16x32_bf16(a0, bj, acc[0][j], 0, 0, 0);
            acc[1][j] = __builtin_amdgcn_mfma_f32_16x16x32_bf16(a1, bj, acc[1][j], 0, 0, 0);
        }
        __syncthreads();
    }

    int b = n0 >> 12, nbase = n0 & 4095;
    if (mt < 2) {
        // LDS transpose: vtT[n(64)][o(128+8 pad)] bf16, 17.4 KB
        unsigned short (*vtT)[136] = (unsigned short(*)[136])smem;
        float sc = (mt == 0) ? QSCALE_LOG2E : 1.0f;
#pragma unroll
        for (int i = 0; i < 2; ++i) {
            int ob = wid * 32 + i * 16 + quad * 4;
#pragma unroll
            for (int j = 0; j < 4; ++j) {
                int nl = j * 16 + low4;
                f32x4 v = acc[i][j];
                unsigned long long d =
                    (unsigned long long)pk2bf(v[0] * sc, v[1] * sc) |
                    ((unsigned long long)pk2bf(v[2] * sc, v[3] * sc) << 32);
                *(unsigned long long*)(&vtT[nl][ob]) = d;
            }
        }
        __syncthreads();
        if (mt == 0) {
            // Q [bh][n][32ch]: 16 lanes share n, cover 128 o -> 4x64B runs
#pragma unroll
            for (int it = 0; it < 4; ++it) {
                int slot = it * 256 + threadIdx.x;
                int n = slot >> 4, c16 = slot & 15;
                s16x8 val = *(const s16x8*)(&vtT[n][c16 * 8]);
                int o = c16 * 8, head = o >> 5, ch = o & 31;
                *(s16x8*)(Q + ((size_t)(b * 4 + head) * NPOS + nbase + n) * 32 + ch) = val;
            }
        } else {
            // K fragment order: wave covers one (c16) x all n -> 2x512B runs
#pragma unroll
            for (int it = 0; it < 4; ++it) {
                int slot = it * 256 + threadIdx.x;
                int c16 = slot >> 6, n = slot & 63;
                s16x8 val = *(const s16x8*)(&vtT[n][c16 * 8]);
                int o = c16 * 8, head = o >> 5, c0h = o & 31;
                int f = c0h >> 4, hh = (c0h >> 3) & 1;
                int nG = nbase + n;
                int bh = b * 4 + head;
                size_t addr = (((size_t)bh * 128 + (nG >> 5)) * 2 + f) * 512
                            + (size_t)((((hh << 5) | (nG & 31)) << 3));
                *(s16x8*)(K + addr) = val;
            }
        }
    } else {
        // V: transpose 128(ch) x 64(n) through LDS, then store fragment-order
        unsigned short* vt = (unsigned short*)smem;   // [128][80] shorts (20 KB)
#pragma unroll
        for (int i = 0; i < 2; ++i) {
            int ol = wid * 32 + i * 16 + quad * 4;
#pragma unroll
            for (int j = 0; j < 4; ++j) {
                int col = j * 16 + low4;
#pragma unroll
                for (int r = 0; r < 4; ++r) vt[(ol + r) * 80 + col] = f2bf(acc[i][j][r]);
            }
        }
        __syncthreads();
#pragma unroll
        for (int rep = 0; rep < 4; ++rep) {
            int idx = rep * 256 + threadIdx.x;
            int row = idx >> 3, c8 = idx & 7;
            s16x8 val = *(const s16x8*)(vt + row * 80 + c8 * 8);   // keys nstart..+8, channel row
            int head = row >> 5, ch = row & 31;
            int bh = b * 4 + head;
            int nstart = nbase + c8 * 8;
            int kc = nstart >> 4, hh = (nstart >> 3) & 1;
            *(s16x8*)(V + ((size_t)(bh * 256 + kc) * 64 + ((hh << 5) | ch)) * 8) = val;
        }
    }
}

// ---------------- kernel 3: attention (verified R13: fragment-order staging,
// counted-vmcnt barrier, setprio) ----------------
__global__ __launch_bounds__(256, 4) void k_attn(const unsigned short* __restrict__ Q,
                                                 const unsigned short* __restrict__ K,
                                                 const unsigned short* __restrict__ V,
                                                 unsigned short* __restrict__ attnO) {
    __shared__ __align__(16) unsigned char smem[2 * 16384];   // 32 KB dbuf; combine reuses buf0
    int bh = blockIdx.x & 15;
    int qt = blockIdx.x >> 4;          // 0..63
    int wid = threadIdx.x >> 6;        // 0..3
    int lane = threadIdx.x & 63;
    int q5 = lane & 31, h = lane >> 5;
    int qg = wid & 1, kh = wid >> 1;
    int q0 = qt * 64 + qg * 32;
    int khk = kh * 2048;

    const unsigned short* Qp = Q + (size_t)bh * NPOS * 32;

    s16x8 bq0 = *(const s16x8*)(Qp + (size_t)(q0 + q5) * 32 + h * 8);
    s16x8 bq1 = *(const s16x8*)(Qp + (size_t)(q0 + q5) * 32 + 16 + h * 8);

    const unsigned short* pKf = K + (size_t)bh * 131072 + lane * 8;
    const unsigned short* pVf = V + (size_t)bh * 131072 + lane * 8;

    auto stage = [&](int bufi, int k0) {
        unsigned char* wb = smem + bufi * 16384 + kh * 8192;
        if (qg == 0) {   // K: contiguous 4KB
            const unsigned short* p = pKf + (size_t)(k0 >> 5) * 1024;
            async_cp16(p,        wb);
            async_cp16(p + 512,  wb + 1024);
            async_cp16(p + 1024, wb + 2048);
            async_cp16(p + 1536, wb + 3072);
        } else {         // V: contiguous 4KB
            const unsigned short* p = pVf + (size_t)(k0 >> 4) * 512;
            async_cp16(p,        wb + 4096);
            async_cp16(p + 512,  wb + 5120);
            async_cp16(p + 1024, wb + 6144);
            async_cp16(p + 1536, wb + 7168);
        }
    };

    f32x16 oT = {};
    f32x2 lacc0 = {0.0f, 0.0f}, lacc1 = {0.0f, 0.0f};
    const int lby = lane * 16;

    stage(0, khk);

#pragma unroll 1
    for (int it = 0; it < 32; ++it) {
        if (it + 1 < 32) {
            stage((it + 1) & 1, khk + (it + 1) * 64);
            asm volatile("s_waitcnt vmcnt(4)" ::: "memory");   // iter-it staged; it+1 in flight
        } else {
            asm volatile("s_waitcnt vmcnt(0)" ::: "memory");
        }
        asm volatile("s_barrier" ::: "memory");

        const unsigned char* kb = smem + (it & 1) * 16384 + kh * 8192;
#pragma unroll
        for (int t = 0; t < 2; ++t) {
            s16x8 ak0 = *(const s16x8*)(kb + t * 2048 + lby);
            s16x8 ak1 = *(const s16x8*)(kb + t * 2048 + 1024 + lby);
            f32x16 s = {};
            __builtin_amdgcn_s_setprio(1);
            s = MFMA32(ak0, bq0, s);
            s = MFMA32(ak1, bq1, s);
            __builtin_amdgcn_s_setprio(0);
            unsigned p[8];
#pragma unroll
            for (int i = 0; i < 8; ++i) {
                float e0 = __builtin_amdgcn_exp2f(s[2 * i]);
                float e1 = __builtin_amdgcn_exp2f(s[2 * i + 1]);
                f32x2 e = {e0, e1};
                if (i & 1) lacc0 += e;
                else       lacc1 += e;
                p[i] = pk2bf(e0, e1);
            }
            plswap(p[0], p[2]); plswap(p[1], p[3]);
            plswap(p[4], p[6]); plswap(p[5], p[7]);
            s16x8 bplo = mk8(p[0], p[1], p[2], p[3]);
            s16x8 bphi = mk8(p[4], p[5], p[6], p[7]);

            s16x8 av0 = *(const s16x8*)(kb + 4096 + (2 * t) * 1024 + lby);
            s16x8 av1 = *(const s16x8*)(kb + 4096 + (2 * t + 1) * 1024 + lby);
            __builtin_amdgcn_s_setprio(1);
            oT = MFMA32(av0, bplo, oT);
            oT = MFMA32(av1, bphi, oT);
            __builtin_amdgcn_s_setprio(0);
        }
        asm volatile("s_barrier" ::: "memory");   // WAR: buf (it&1) free to restage
    }

    float lsum = lacc0[0] + lacc0[1] + lacc1[0] + lacc1[1];
    lsum += __shfl_xor(lsum, 32);

    if (kh) {
        float* area = (float*)(smem + qg * 4352);
#pragma unroll
        for (int j = 0; j < 4; ++j)
            *(f32x4*)(area + j * 256 + lane * 4) =
                f32x4{oT[4 * j], oT[4 * j + 1], oT[4 * j + 2], oT[4 * j + 3]};
        area[1024 + lane] = lsum;
    }
    __syncthreads();
    if (!kh) {
        const float* area = (const float*)(smem + qg * 4352);
        lsum += area[1024 + lane];
        float inv = 1.0f / lsum;
        int b = bh >> 2, head = bh & 3;
        int n = q0 + q5;
        unsigned short* base = attnO + ((size_t)(b * NPOS + n)) * CHID + head * 32 + 4 * h;
#pragma unroll
        for (int j = 0; j < 4; ++j) {
            f32x4 r = *(const f32x4*)(area + j * 256 + lane * 4);
            unsigned long long d =
                (unsigned long long)pk2bf((oT[4 * j] + r[0]) * inv, (oT[4 * j + 1] + r[1]) * inv) |
                ((unsigned long long)pk2bf((oT[4 * j + 2] + r[2]) * inv, (oT[4 * j + 3] + r[3]) * inv) << 32);
            *(unsigned long long*)(base + 8 * j) = d;
        }
    }
}

// ---------------- kernel 4: output projection GEMM + bias, LDS-staged ----------------
__global__ __launch_bounds__(256, 4) void k_out(const unsigned short* __restrict__ wo,
                                                const unsigned short* __restrict__ attnO,
                                                const float* __restrict__ bias,
                                                float* __restrict__ out) {
    __shared__ __align__(16) unsigned char smem[2 * 12288];   // 24 KB
    int mt = blockIdx.x & 1;
    int nt = blockIdx.x >> 1;
    int wid = threadIdx.x >> 6, lane = threadIdx.x & 63;
    int quad = lane >> 4, low4 = lane & 15;
    int o0 = mt * 128, n0 = nt * 64;
    int lb = lane * 16;

    const unsigned short* srcA0 = wo + (size_t)(o0 + wid * 32 + low4) * CHID + quad * 8;
    const unsigned short* srcA1 = srcA0 + 16 * CHID;
    const unsigned short* srcB  = attnO + (size_t)(n0 + wid * 16 + low4) * CHID + quad * 8;
    int dA0 = wid * 2048, dA1 = dA0 + 1024, dB = 8192 + wid * 1024;

    async_cp16(srcA0, smem + dA0 + lb);
    async_cp16(srcA1, smem + dA1 + lb);
    async_cp16(srcB,  smem + dB  + lb);
    __syncthreads();

    f32x4 acc[2][4] = {};
    for (int c = 0; c < 4; ++c) {
        if (c < 3) {
            unsigned char* nxt = smem + ((c + 1) & 1) * 12288;
            async_cp16(srcA0 + (c + 1) * 32, nxt + dA0 + lb);
            async_cp16(srcA1 + (c + 1) * 32, nxt + dA1 + lb);
            async_cp16(srcB  + (c + 1) * 32, nxt + dB  + lb);
        }
        const unsigned char* cur = smem + (c & 1) * 12288;
        s16x8 a0 = *(const s16x8*)(cur + wid * 2048 + lb);
        s16x8 a1 = *(const s16x8*)(cur + wid * 2048 + 1024 + lb);
#pragma unroll
        for (int j = 0; j < 4; ++j) {
            s16x8 bj = *(const s16x8*)(cur + 8192 + j * 1024 + lb);
            acc[0][j] = __builtin_amdgcn_mfma_f32_16x16x32_bf16(a0, bj, acc[0][j], 0, 0, 0);
            acc[1][j] = __builtin_amdgcn_mfma_f32_16x16x32_bf16(a1, bj, acc[1][j], 0, 0, 0);
        }
        __syncthreads();
    }

    // Epilogue: bounce through LDS in two 64(o) x 64(n) fp32 half-tiles,
    // then float4 stores (16 lanes -> 256B contiguous runs).
    float (*larea)[68] = (float(*)[68])smem;   // 64*68*4 = 17.4 KB
    int b = n0 >> 12, nb = n0 & 4095;
#pragma unroll
    for (int half = 0; half < 2; ++half) {
        if ((wid >> 1) == half) {
#pragma unroll
            for (int i = 0; i < 2; ++i) {
                int row = (wid & 1) * 32 + i * 16 + quad * 4;
                int o = o0 + half * 64 + row;
#pragma unroll
                for (int j = 0; j < 4; ++j) {
                    int nl = j * 16 + low4;
#pragma unroll
                    for (int r = 0; r < 4; ++r)
                        larea[row + r][nl] = acc[i][j][r] + bias[o + r];
                }
            }
        }
        __syncthreads();
#pragma unroll
        for (int it = 0; it < 4; ++it) {
            int slot = it * 256 + threadIdx.x;
            int row = slot >> 4, nn4 = (slot & 15) * 4;
            int o = o0 + half * 64 + row;
            f32x4 v = *(const f32x4*)(&larea[row][nn4]);
            *(f32x4*)(out + ((size_t)(b * CIN + o)) * NPOS + nb + nn4) = v;
        }
        __syncthreads();
    }
}

extern "C" void kernel_launch(void* const* d_in, const int* in_sizes, int n_in,
                              void* d_out, int out_size, void* d_ws, size_t ws_size,
                              hipStream_t stream) {
    const float* x    = (const float*)d_in[0];
    const float* wqkv = (const float*)d_in[1];
    const float* wout = (const float*)d_in[2];
    const float* bout = (const float*)d_in[3];
    float* out = (float*)d_out;

    unsigned short* Q       = (unsigned short*)d_ws;
    unsigned short* K       = Q + (size_t)BH * NPOS * 32;       // +4 MB (fragment order)
    unsigned short* V       = K + (size_t)BH * NPOS * 32;       // +4 MB (fragment order)
    unsigned short* attnO   = V + (size_t)BH * 32 * NPOS;       // +4 MB
    unsigned short* xT      = attnO + (size_t)NTOT * CHID;      // +4 MB
    unsigned short* wqkv_bf = xT + (size_t)NTOT * CIN;          // +8 MB
    unsigned short* wout_bf = wqkv_bf + QKV_O * CIN;            // +192 KB

    k_prep<<<PTILES + (QKV_O * CIN + 255) / 256, 256, 0, stream>>>(x, xT, wqkv, wout, wqkv_bf, wout_bf);
    k_qkv<<<3 * (NTOT / 64), 256, 0, stream>>>(wqkv_bf, xT, Q, K, V);
    k_attn<<<(NPOS / 64) * BH, 256, 0, stream>>>(Q, K, V, attnO);
    k_out<<<2 * (NTOT / 64), 256, 0, stream>>>(wout_bf, attnO, bout, out);
}